// Round 2
// baseline (432.346 us; speedup 1.0000x reference)
//
#include <hip/hip_runtime.h>

// Flash attention fwd: fp32 I/O, bf16 MFMA, fp32 softmax math.
// BH=32, S=2048, D=64, additive mask [2,S,S] tiled bh%2.
// R10: R9's occupancy doubling without the spills. R9's launch_bounds(512,4)
// let the backend target 8 waves/EU -> 64 VGPR -> scratch spills (hbm 3x,
// WRITE 47MB). Fixes: (a) amdgpu_waves_per_eu(4,4) pins the reg budget at
// 128; (b) K/V pair is LDS double-buffered (80 KB total: 2x32 KB K/V pair
// + 16 KB single-tile sP), so prefetch regs are live only half the
// iteration; (c) per-tile QK->sP->PV serialization halves live p/mask regs.
// One barrier per 128-col pair; TLP (4 waves/SIMD) replaces R8's ILP.

constexpr int cBH = 32;
constexpr int cS  = 2048;
constexpr int cD  = 64;
constexpr int cQT = 128;            // 8 waves x 16 q-rows
constexpr int cNP = cS / 128;       // 16 pairs of 64-wide k-tiles

typedef __bf16 bf16x8 __attribute__((ext_vector_type(8)));
typedef __bf16 bf16x4 __attribute__((ext_vector_type(4)));
typedef float  f32x4  __attribute__((ext_vector_type(4)));

__device__ __forceinline__ unsigned short bfbits(float f) {
    return __builtin_bit_cast(unsigned short, (__bf16)f);
}
__device__ __forceinline__ bf16x4 pack4(f32x4 a) {
    bf16x4 r;
    r[0] = (__bf16)a[0]; r[1] = (__bf16)a[1];
    r[2] = (__bf16)a[2]; r[3] = (__bf16)a[3];
    return r;
}
__device__ __forceinline__ bf16x8 pack8s(f32x4 a, f32x4 b, float s) {
    bf16x8 r;
    r[0] = (__bf16)(a[0]*s); r[1] = (__bf16)(a[1]*s);
    r[2] = (__bf16)(a[2]*s); r[3] = (__bf16)(a[3]*s);
    r[4] = (__bf16)(b[0]*s); r[5] = (__bf16)(b[1]*s);
    r[6] = (__bf16)(b[2]*s); r[7] = (__bf16)(b[3]*s);
    return r;
}
__device__ __forceinline__ int fkey(int row) {   // sP swizzle key, rows 0..15
    return ((row & 7) ^ ((row >> 3) << 1)) & 7;
}
__device__ __forceinline__ int gkey(int d) {     // sV swizzle key
    return (d ^ (d >> 3)) & 7;
}

__global__ __launch_bounds__(512)
__attribute__((amdgpu_waves_per_eu(4, 4)))
void sdpa_flash_kernel(const float* __restrict__ q,
                       const float* __restrict__ k,
                       const float* __restrict__ v,
                       const float* __restrict__ mask,
                       float* __restrict__ out)
{
    // sK[buf][t]: [krow][d], key krow&7.  sV[buf][t]: [d][krow], key gkey(d).
    // sP[wave]: [qrow 0..15][kcol], key fkey(qrow) — reused per tile.
    __shared__ unsigned short sK[2][2][64 * 64];
    __shared__ unsigned short sV[2][2][64 * 64];
    __shared__ unsigned short sP[8][16 * 64];

    const int tid  = threadIdx.x;
    const int wv   = tid >> 6;                          // 0..7
    const int lane = tid & 63;
    const int quad = lane >> 4;
    const int ln   = lane & 15;

    const int fid = blockIdx.x;
    const int bh  = (fid & 7) | ((fid >> 7) << 3);      // XCD-local heads
    const int qb  = ((fid >> 3) & 15) * cQT;
    const int mb  = bh & 1;

    const float L2E = 1.4426950408889634f;

    // ---- Q fragments, pre-scaled by 0.125*log2(e): aq[ks] ----
    bf16x8 aq[2];
    {
        const float* qp = q + ((size_t)bh * cS + qb + wv * 16 + ln) * cD + quad * 8;
        aq[0] = pack8s(*(const f32x4*)(qp),      *(const f32x4*)(qp + 4),  0.125f * L2E);
        aq[1] = pack8s(*(const f32x4*)(qp + 32), *(const f32x4*)(qp + 36), 0.125f * L2E);
    }

    f32x4 acc[4];
    float lsum[4];
#pragma unroll
    for (int dt = 0; dt < 4; ++dt) {
        acc[dt] = (f32x4){0.f, 0.f, 0.f, 0.f};
        lsum[dt] = 0.f;
    }

    // ---- staging geometry: 512 threads; chunk j = floats j*2048 + tid*4 ----
    const int sr0 = tid >> 4;                 // 0..31
    const int c4  = (tid & 15) << 2;
    const int ka0 = sr0 * 64 + (((c4 >> 3) ^ (sr0 & 7)) << 3) + (c4 & 7);
    const float* kg = k + (size_t)bh * cS * cD;
    const float* vg = v + (size_t)bh * cS * cD;
    const float* mq = mask + (size_t)mb * cS * cS
                           + (size_t)(qb + wv * 16 + quad * 4) * cS + ln;

    // ---- prologue: stage pair 0 into buffer 0 ----
#pragma unroll
    for (int t = 0; t < 2; ++t)
#pragma unroll
        for (int j = 0; j < 2; ++j) {
            f32x4 kj = *(const f32x4*)(kg + t * 4096 + j * 2048 + tid * 4);
            f32x4 vj = *(const f32x4*)(vg + t * 4096 + j * 2048 + tid * 4);
            *(bf16x4*)&sK[0][t][ka0 + j * 2048] = pack4(kj);
#pragma unroll
            for (int i = 0; i < 4; ++i) {
                int d = c4 + i;
                sV[0][t][d * 64 + ((((j * 4) + (sr0 >> 3)) ^ gkey(d)) << 3) + (sr0 & 7)]
                    = bfbits(vj[i]);
            }
        }

    for (int pt = 0; pt < cNP; ++pt) {
        const int cur  = pt & 1;
        const int nxt  = cur ^ 1;
        const int base = pt * 2;
        const bool more = (pt + 1 < cNP);
        const int nb = more ? base + 2 : base;      // clamped: uncond. loads

        __syncthreads();   // buf[cur] staged & visible; buf[nxt] reads done

        // ---- issue next-pair global loads (drained into LDS after PV0) ----
        f32x4 KP[2][2], VP[2][2];
#pragma unroll
        for (int t = 0; t < 2; ++t)
#pragma unroll
            for (int j = 0; j < 2; ++j) {
                KP[t][j] = *(const f32x4*)(kg + (size_t)(nb + t) * 4096 + j * 2048 + tid * 4);
                VP[t][j] = *(const f32x4*)(vg + (size_t)(nb + t) * 4096 + j * 2048 + tid * 4);
            }

        // ---- mask for tile 0 ----
        float mcE[4][4];
#pragma unroll
        for (int nt = 0; nt < 4; ++nt)
#pragma unroll
            for (int r = 0; r < 4; ++r)
                mcE[nt][r] = mq[(size_t)r * cS + base * 64 + nt * 16];

        // ---- QK tile 0 ----
        float pE[4][4];
#pragma unroll
        for (int nt = 0; nt < 4; ++nt) {
            const int rb = (nt * 16 + ln) * 64;
            const int x0 = (quad ^ (ln & 7)) << 3;
            const int x1 = ((4 | quad) ^ (ln & 7)) << 3;
            bf16x8 b0 = *(const bf16x8*)(&sK[cur][0][rb + x0]);
            bf16x8 b1 = *(const bf16x8*)(&sK[cur][0][rb + x1]);
            f32x4 ce = (f32x4){0.f,0.f,0.f,0.f};
            ce = __builtin_amdgcn_mfma_f32_16x16x32_bf16(aq[0], b0, ce, 0, 0, 0);
            ce = __builtin_amdgcn_mfma_f32_16x16x32_bf16(aq[1], b1, ce, 0, 0, 0);
#pragma unroll
            for (int r = 0; r < 4; ++r)
                pE[nt][r] = __builtin_amdgcn_exp2f(fmaf(mcE[nt][r], L2E, ce[r]));
        }
#pragma unroll
        for (int r = 0; r < 4; ++r)
            lsum[r] += (pE[0][r] + pE[1][r]) + (pE[2][r] + pE[3][r]);

        // ---- P -> sP (tile 0), then PV tile 0 ----
#pragma unroll
        for (int nt = 0; nt < 4; ++nt)
#pragma unroll
            for (int r = 0; r < 4; ++r) {
                int row = quad * 4 + r;
                int blk = ((nt * 2 + (ln >> 3)) ^ fkey(row)) << 3;
                sP[wv][row * 64 + blk + (ln & 7)] = bfbits(pE[nt][r]);
            }
        // same-wave DS ordering: reads below drain after these writes
        {
            const unsigned short* sPt = &sP[wv][0];
            const unsigned short* sVt = sV[cur][0];
#pragma unroll
            for (int ks = 0; ks < 2; ++ks) {
                bf16x8 ap = *(const bf16x8*)(
                    &sPt[ln * 64 + ((((ks << 2) | quad) ^ fkey(ln)) << 3)]);
#pragma unroll
                for (int dt = 0; dt < 4; ++dt) {
                    int d = dt * 16 + ln;
                    bf16x8 bv = *(const bf16x8*)(
                        &sVt[d * 64 + ((((ks << 2) | quad) ^ gkey(d)) << 3)]);
                    acc[dt] = __builtin_amdgcn_mfma_f32_16x16x32_bf16(ap, bv, acc[dt], 0, 0, 0);
                }
            }
        }

        // ---- drain next-pair loads into buf[nxt] (frees 32 VGPRs) ----
        if (more) {
#pragma unroll
            for (int t = 0; t < 2; ++t)
#pragma unroll
                for (int j = 0; j < 2; ++j) {
                    *(bf16x4*)&sK[nxt][t][ka0 + j * 2048] = pack4(KP[t][j]);
#pragma unroll
                    for (int i = 0; i < 4; ++i) {
                        int d = c4 + i;
                        sV[nxt][t][d * 64
                            + ((((j * 4) + (sr0 >> 3)) ^ gkey(d)) << 3) + (sr0 & 7)]
                            = bfbits(VP[t][j][i]);
                    }
                }
        }

        // ---- mask for tile 1 ----
        float mcO[4][4];
#pragma unroll
        for (int nt = 0; nt < 4; ++nt)
#pragma unroll
            for (int r = 0; r < 4; ++r)
                mcO[nt][r] = mq[(size_t)r * cS + base * 64 + nt * 16 + 64];

        // ---- QK tile 1 ----
        float pO[4][4];
#pragma unroll
        for (int nt = 0; nt < 4; ++nt) {
            const int rb = (nt * 16 + ln) * 64;
            const int x0 = (quad ^ (ln & 7)) << 3;
            const int x1 = ((4 | quad) ^ (ln & 7)) << 3;
            bf16x8 b0 = *(const bf16x8*)(&sK[cur][1][rb + x0]);
            bf16x8 b1 = *(const bf16x8*)(&sK[cur][1][rb + x1]);
            f32x4 co = (f32x4){0.f,0.f,0.f,0.f};
            co = __builtin_amdgcn_mfma_f32_16x16x32_bf16(aq[0], b0, co, 0, 0, 0);
            co = __builtin_amdgcn_mfma_f32_16x16x32_bf16(aq[1], b1, co, 0, 0, 0);
#pragma unroll
            for (int r = 0; r < 4; ++r)
                pO[nt][r] = __builtin_amdgcn_exp2f(fmaf(mcO[nt][r], L2E, co[r]));
        }
#pragma unroll
        for (int r = 0; r < 4; ++r)
            lsum[r] += (pO[0][r] + pO[1][r]) + (pO[2][r] + pO[3][r]);

        // ---- P -> sP (tile 1), then PV tile 1 ----
#pragma unroll
        for (int nt = 0; nt < 4; ++nt)
#pragma unroll
            for (int r = 0; r < 4; ++r) {
                int row = quad * 4 + r;
                int blk = ((nt * 2 + (ln >> 3)) ^ fkey(row)) << 3;
                sP[wv][row * 64 + blk + (ln & 7)] = bfbits(pO[nt][r]);
            }
        {
            const unsigned short* sPt = &sP[wv][0];
            const unsigned short* sVt = sV[cur][1];
#pragma unroll
            for (int ks = 0; ks < 2; ++ks) {
                bf16x8 ap = *(const bf16x8*)(
                    &sPt[ln * 64 + ((((ks << 2) | quad) ^ fkey(ln)) << 3)]);
#pragma unroll
                for (int dt = 0; dt < 4; ++dt) {
                    int d = dt * 16 + ln;
                    bf16x8 bv = *(const bf16x8*)(
                        &sVt[d * 64 + ((((ks << 2) | quad) ^ gkey(d)) << 3)]);
                    acc[dt] = __builtin_amdgcn_mfma_f32_16x16x32_bf16(ap, bv, acc[dt], 0, 0, 0);
                }
            }
        }
    }

    // ---- epilogue: row-sum reduce over 16 k-col lanes, O = acc / l ----
#pragma unroll
    for (int off = 1; off < 16; off <<= 1)
#pragma unroll
        for (int r = 0; r < 4; ++r)
            lsum[r] += __shfl_xor(lsum[r], off, 64);
    {
        float rl[4];
#pragma unroll
        for (int r = 0; r < 4; ++r) rl[r] = 1.0f / lsum[r];
#pragma unroll
        for (int dt = 0; dt < 4; ++dt)
#pragma unroll
            for (int r = 0; r < 4; ++r)
                out[((size_t)bh * cS + qb + wv * 16 + quad * 4 + r) * cD
                    + dt * 16 + ln] = acc[dt][r] * rl[r];
    }
}

extern "C" void kernel_launch(void* const* d_in, const int* in_sizes, int n_in,
                              void* d_out, int out_size, void* d_ws, size_t ws_size,
                              hipStream_t stream) {
    const float* q = (const float*)d_in[0];
    const float* k = (const float*)d_in[1];
    const float* v = (const float*)d_in[2];
    const float* m = (const float*)d_in[3];
    float* o = (float*)d_out;
    sdpa_flash_kernel<<<dim3(512), 512, 0, stream>>>(q, k, v, m, o);
}

// Round 3
// 199.171 us; speedup vs baseline: 2.1707x; 2.1707x over previous
//
#include <hip/hip_runtime.h>

// Flash attention fwd: fp32 I/O, bf16 MFMA, fp32 softmax math.
// BH=32, S=2048, D=64, additive mask [2,S,S] tiled bh%2.
// R11: occupancy via blocks/CU, not waves/block. R9/R10 proved 512-thread
// blocks make the backend pick a 64-VGPR budget and spill (hbm 3-6x).
// Stay in the proven 256-thread regime (R8 allocated 128 VGPR cleanly):
// QT=64 (4 waves x 16 q-rows), grid 1024 = 4 blocks/CU, LDS 40 KB exactly
// (sK pair 16K + sV pair 16K + per-wave single-tile sP 8K) -> 16 waves/CU
// = 4 waves/SIMD. R8 staging geometry + register prefetch retained; sP is
// reused tile0->tile1 (same-wave DS ordering); masks loaded per-tile to
// keep peak pressure ~125 regs.

constexpr int cBH = 32;
constexpr int cS  = 2048;
constexpr int cD  = 64;
constexpr int cQT = 64;             // 4 waves x 16 q-rows
constexpr int cNP = cS / 128;       // 16 pairs of 64-wide k-tiles

typedef __bf16 bf16x8 __attribute__((ext_vector_type(8)));
typedef __bf16 bf16x4 __attribute__((ext_vector_type(4)));
typedef float  f32x4  __attribute__((ext_vector_type(4)));

__device__ __forceinline__ unsigned short bfbits(float f) {
    return __builtin_bit_cast(unsigned short, (__bf16)f);
}
__device__ __forceinline__ bf16x4 pack4(f32x4 a) {
    bf16x4 r;
    r[0] = (__bf16)a[0]; r[1] = (__bf16)a[1];
    r[2] = (__bf16)a[2]; r[3] = (__bf16)a[3];
    return r;
}
__device__ __forceinline__ bf16x8 pack8s(f32x4 a, f32x4 b, float s) {
    bf16x8 r;
    r[0] = (__bf16)(a[0]*s); r[1] = (__bf16)(a[1]*s);
    r[2] = (__bf16)(a[2]*s); r[3] = (__bf16)(a[3]*s);
    r[4] = (__bf16)(b[0]*s); r[5] = (__bf16)(b[1]*s);
    r[6] = (__bf16)(b[2]*s); r[7] = (__bf16)(b[3]*s);
    return r;
}
__device__ __forceinline__ int fkey(int row) {   // sP swizzle key, rows 0..15
    return ((row & 7) ^ ((row >> 3) << 1)) & 7;
}
__device__ __forceinline__ int gkey(int d) {     // sV swizzle key
    return (d ^ (d >> 3)) & 7;
}

__global__ __launch_bounds__(256, 2)
void sdpa_flash_kernel(const float* __restrict__ q,
                       const float* __restrict__ k,
                       const float* __restrict__ v,
                       const float* __restrict__ mask,
                       float* __restrict__ out)
{
    // sK[t]: [krow][d], key krow&7.  sV[t]: [d][krow] (V^T), key gkey(d).
    // sP[wave]: [qrow 0..15][kcol], key fkey(qrow) — reused per tile.
    __shared__ unsigned short sK[2][64 * 64];
    __shared__ unsigned short sV[2][64 * 64];
    __shared__ unsigned short sP[4][16 * 64];

    const int tid  = threadIdx.x;
    const int wv   = tid >> 6;                          // 0..3
    const int lane = tid & 63;
    const int quad = lane >> 4;
    const int ln   = lane & 15;

    const int fid = blockIdx.x;                         // 0..1023
    const int bh  = (fid & 7) | ((fid >> 8) << 3);      // XCD-local heads
    const int qb  = ((fid >> 3) & 31) * cQT;
    const int mb  = bh & 1;

    const float L2E = 1.4426950408889634f;

    // ---- Q fragments, pre-scaled by 0.125*log2(e): aq[ks] ----
    bf16x8 aq[2];
    {
        const float* qp = q + ((size_t)bh * cS + qb + wv * 16 + ln) * cD + quad * 8;
        aq[0] = pack8s(*(const f32x4*)(qp),      *(const f32x4*)(qp + 4),  0.125f * L2E);
        aq[1] = pack8s(*(const f32x4*)(qp + 32), *(const f32x4*)(qp + 36), 0.125f * L2E);
    }

    f32x4 acc[4];
    float lsum[4];
#pragma unroll
    for (int dt = 0; dt < 4; ++dt) {
        acc[dt] = (f32x4){0.f, 0.f, 0.f, 0.f};
        lsum[dt] = 0.f;
    }

    // ---- staging geometry: 256 threads; chunk j = floats j*1024 + tid*4 ----
    const int sr0 = tid >> 4;                 // 0..15
    const int c4  = (tid & 15) << 2;
    const int ka0 = sr0 * 64 + (((c4 >> 3) ^ (sr0 & 7)) << 3) + (c4 & 7);
    const float* kg = k + (size_t)bh * cS * cD;
    const float* vg = v + (size_t)bh * cS * cD;
    const float* mq = mask + (size_t)mb * cS * cS
                           + (size_t)(qb + wv * 16 + quad * 4) * cS + ln;

    // ---- prologue: stage pair 0 (tiles 0 and 1) directly ----
#pragma unroll
    for (int t = 0; t < 2; ++t)
#pragma unroll
        for (int j = 0; j < 4; ++j) {
            f32x4 kj = *(const f32x4*)(kg + t * 4096 + j * 1024 + tid * 4);
            f32x4 vj = *(const f32x4*)(vg + t * 4096 + j * 1024 + tid * 4);
            *(bf16x4*)&sK[t][ka0 + j * 1024] = pack4(kj);
#pragma unroll
            for (int i = 0; i < 4; ++i) {
                int d = c4 + i;
                sV[t][d * 64 + ((((j * 2) + (sr0 >> 3)) ^ gkey(d)) << 3) + (sr0 & 7)]
                    = bfbits(vj[i]);
            }
        }

    for (int pt = 0; pt < cNP; ++pt) {
        const int base = pt * 2;
        const bool more = (pt + 1 < cNP);
        const int nb = more ? base + 2 : base;      // clamped: uncond. loads

        // ---- prefetch next pair K/V into registers ----
        f32x4 KPe[4], VPe[4], KPo[4], VPo[4];
#pragma unroll
        for (int j = 0; j < 4; ++j) {
            KPe[j] = *(const f32x4*)(kg + (size_t)nb * 4096 + j * 1024 + tid * 4);
            VPe[j] = *(const f32x4*)(vg + (size_t)nb * 4096 + j * 1024 + tid * 4);
            KPo[j] = *(const f32x4*)(kg + (size_t)(nb + 1) * 4096 + j * 1024 + tid * 4);
            VPo[j] = *(const f32x4*)(vg + (size_t)(nb + 1) * 4096 + j * 1024 + tid * 4);
        }
        // ---- tile 0 mask (used after QK0) ----
        float mcE[4][4];
#pragma unroll
        for (int nt = 0; nt < 4; ++nt)
#pragma unroll
            for (int r = 0; r < 4; ++r)
                mcE[nt][r] = mq[(size_t)r * cS + base * 64 + nt * 16];

        __syncthreads();                            // pair staged & visible

        // ---- QK tile 0 ----
        float pE[4][4];
#pragma unroll
        for (int nt = 0; nt < 4; ++nt) {
            const int rb = (nt * 16 + ln) * 64;
            const int x0 = (quad ^ (ln & 7)) << 3;
            const int x1 = ((4 | quad) ^ (ln & 7)) << 3;
            bf16x8 b0 = *(const bf16x8*)(&sK[0][rb + x0]);
            bf16x8 b1 = *(const bf16x8*)(&sK[0][rb + x1]);
            f32x4 ce = (f32x4){0.f,0.f,0.f,0.f};
            ce = __builtin_amdgcn_mfma_f32_16x16x32_bf16(aq[0], b0, ce, 0, 0, 0);
            ce = __builtin_amdgcn_mfma_f32_16x16x32_bf16(aq[1], b1, ce, 0, 0, 0);
#pragma unroll
            for (int r = 0; r < 4; ++r)
                pE[nt][r] = __builtin_amdgcn_exp2f(fmaf(mcE[nt][r], L2E, ce[r]));
        }
#pragma unroll
        for (int r = 0; r < 4; ++r)
            lsum[r] += (pE[0][r] + pE[1][r]) + (pE[2][r] + pE[3][r]);

        // ---- P -> sP (tile 0) ----
#pragma unroll
        for (int nt = 0; nt < 4; ++nt)
#pragma unroll
            for (int r = 0; r < 4; ++r) {
                int row = quad * 4 + r;
                int blk = ((nt * 2 + (ln >> 3)) ^ fkey(row)) << 3;
                sP[wv][row * 64 + blk + (ln & 7)] = bfbits(pE[nt][r]);
            }

        // ---- tile 1 mask (issued under PV tile 0's latency) ----
        float mcO[4][4];
#pragma unroll
        for (int nt = 0; nt < 4; ++nt)
#pragma unroll
            for (int r = 0; r < 4; ++r)
                mcO[nt][r] = mq[(size_t)r * cS + base * 64 + nt * 16 + 64];

        // ---- PV tile 0 (same-wave DS ordering after sP writes) ----
        {
            const unsigned short* sPt = &sP[wv][0];
            const unsigned short* sVt = sV[0];
#pragma unroll
            for (int ks = 0; ks < 2; ++ks) {
                bf16x8 ap = *(const bf16x8*)(
                    &sPt[ln * 64 + ((((ks << 2) | quad) ^ fkey(ln)) << 3)]);
#pragma unroll
                for (int dt = 0; dt < 4; ++dt) {
                    int d = dt * 16 + ln;
                    bf16x8 bv = *(const bf16x8*)(
                        &sVt[d * 64 + ((((ks << 2) | quad) ^ gkey(d)) << 3)]);
                    acc[dt] = __builtin_amdgcn_mfma_f32_16x16x32_bf16(ap, bv, acc[dt], 0, 0, 0);
                }
            }
        }

        // ---- QK tile 1 ----
        float pO[4][4];
#pragma unroll
        for (int nt = 0; nt < 4; ++nt) {
            const int rb = (nt * 16 + ln) * 64;
            const int x0 = (quad ^ (ln & 7)) << 3;
            const int x1 = ((4 | quad) ^ (ln & 7)) << 3;
            bf16x8 b0 = *(const bf16x8*)(&sK[1][rb + x0]);
            bf16x8 b1 = *(const bf16x8*)(&sK[1][rb + x1]);
            f32x4 co = (f32x4){0.f,0.f,0.f,0.f};
            co = __builtin_amdgcn_mfma_f32_16x16x32_bf16(aq[0], b0, co, 0, 0, 0);
            co = __builtin_amdgcn_mfma_f32_16x16x32_bf16(aq[1], b1, co, 0, 0, 0);
#pragma unroll
            for (int r = 0; r < 4; ++r)
                pO[nt][r] = __builtin_amdgcn_exp2f(fmaf(mcO[nt][r], L2E, co[r]));
        }
#pragma unroll
        for (int r = 0; r < 4; ++r)
            lsum[r] += (pO[0][r] + pO[1][r]) + (pO[2][r] + pO[3][r]);

        // ---- P -> sP (tile 1, reuse buffer), then PV tile 1 ----
#pragma unroll
        for (int nt = 0; nt < 4; ++nt)
#pragma unroll
            for (int r = 0; r < 4; ++r) {
                int row = quad * 4 + r;
                int blk = ((nt * 2 + (ln >> 3)) ^ fkey(row)) << 3;
                sP[wv][row * 64 + blk + (ln & 7)] = bfbits(pO[nt][r]);
            }
        {
            const unsigned short* sPt = &sP[wv][0];
            const unsigned short* sVt = sV[1];
#pragma unroll
            for (int ks = 0; ks < 2; ++ks) {
                bf16x8 ap = *(const bf16x8*)(
                    &sPt[ln * 64 + ((((ks << 2) | quad) ^ fkey(ln)) << 3)]);
#pragma unroll
                for (int dt = 0; dt < 4; ++dt) {
                    int d = dt * 16 + ln;
                    bf16x8 bv = *(const bf16x8*)(
                        &sVt[d * 64 + ((((ks << 2) | quad) ^ gkey(d)) << 3)]);
                    acc[dt] = __builtin_amdgcn_mfma_f32_16x16x32_bf16(ap, bv, acc[dt], 0, 0, 0);
                }
            }
        }

        __syncthreads();                            // pair reads complete

        // ---- stage next pair from registers ----
        if (more) {
#pragma unroll
            for (int j = 0; j < 4; ++j) {
                *(bf16x4*)&sK[0][ka0 + j * 1024] = pack4(KPe[j]);
                *(bf16x4*)&sK[1][ka0 + j * 1024] = pack4(KPo[j]);
#pragma unroll
                for (int i = 0; i < 4; ++i) {
                    int d = c4 + i;
                    int va = d * 64 + ((((j * 2) + (sr0 >> 3)) ^ gkey(d)) << 3) + (sr0 & 7);
                    sV[0][va] = bfbits(VPe[j][i]);
                    sV[1][va] = bfbits(VPo[j][i]);
                }
            }
        }
    }

    // ---- epilogue: row-sum reduce over 16 k-col lanes, O = acc / l ----
#pragma unroll
    for (int off = 1; off < 16; off <<= 1)
#pragma unroll
        for (int r = 0; r < 4; ++r)
            lsum[r] += __shfl_xor(lsum[r], off, 64);
    {
        float rl[4];
#pragma unroll
        for (int r = 0; r < 4; ++r) rl[r] = 1.0f / lsum[r];
#pragma unroll
        for (int dt = 0; dt < 4; ++dt)
#pragma unroll
            for (int r = 0; r < 4; ++r)
                out[((size_t)bh * cS + qb + wv * 16 + quad * 4 + r) * cD
                    + dt * 16 + ln] = acc[dt][r] * rl[r];
    }
}

extern "C" void kernel_launch(void* const* d_in, const int* in_sizes, int n_in,
                              void* d_out, int out_size, void* d_ws, size_t ws_size,
                              hipStream_t stream) {
    const float* q = (const float*)d_in[0];
    const float* k = (const float*)d_in[1];
    const float* v = (const float*)d_in[2];
    const float* m = (const float*)d_in[3];
    float* o = (float*)d_out;
    sdpa_flash_kernel<<<dim3(1024), 256, 0, stream>>>(q, k, v, m, o);
}

// Round 4
// 182.531 us; speedup vs baseline: 2.3686x; 1.0912x over previous
//
#include <hip/hip_runtime.h>

// Flash attention fwd: fp32 I/O, bf16 MFMA, fp32 softmax math.
// BH=32, S=2048, D=64, additive mask [2,S,S] tiled bh%2.
// R12: kill the LDS pipe bottleneck. Hand-count of R8 (best, 98us): ~1100
// LDS cycles per wave-iter -> ~59us of DS-pipe serialization per CU; the
// sP round-trip (P: regs->LDS->regs for PV's A operand) is 42% of it.
// Swapped QK^T via 32x32x16 MFMA (T12): S^T = mfma(A=K, B=Q) puts each
// q-row's P lane-local (q = lane&31); P->A-frag redistribution is pure
// VALU (bf16 pack + v_permlane32_swap_b32, lanes l<->l+32), zero DS ops.
// sP deleted: LDS 64->32 KB, lsum 8 regs->1, mask loads 64 scalars->16
// f32x4. Grid 512 = 2 blocks/CU regardless of VGPR (<=256 per
// launch_bounds(256,2)), so extra register pressure is free.

constexpr int cBH = 32;
constexpr int cS  = 2048;
constexpr int cD  = 64;
constexpr int cQT = 128;            // 4 waves x 32 q-rows
constexpr int cNP = cS / 128;       // 16 pairs of 64-wide k-tiles

typedef __bf16 bf16x8 __attribute__((ext_vector_type(8)));
typedef __bf16 bf16x4 __attribute__((ext_vector_type(4)));
typedef float  f32x4  __attribute__((ext_vector_type(4)));
typedef float  f32x16 __attribute__((ext_vector_type(16)));
typedef unsigned int u32x4 __attribute__((ext_vector_type(4)));

__device__ __forceinline__ unsigned short bfbits(float f) {
    return __builtin_bit_cast(unsigned short, (__bf16)f);
}
__device__ __forceinline__ bf16x4 pack4(f32x4 a) {
    bf16x4 r;
    r[0] = (__bf16)a[0]; r[1] = (__bf16)a[1];
    r[2] = (__bf16)a[2]; r[3] = (__bf16)a[3];
    return r;
}
__device__ __forceinline__ bf16x8 pack8s(f32x4 a, f32x4 b, float s) {
    bf16x8 r;
    r[0] = (__bf16)(a[0]*s); r[1] = (__bf16)(a[1]*s);
    r[2] = (__bf16)(a[2]*s); r[3] = (__bf16)(a[3]*s);
    r[4] = (__bf16)(b[0]*s); r[5] = (__bf16)(b[1]*s);
    r[6] = (__bf16)(b[2]*s); r[7] = (__bf16)(b[3]*s);
    return r;
}
__device__ __forceinline__ int gkey(int d) {     // sV swizzle key (d 0..63)
    return (d ^ (d >> 3)) & 7;
}

__global__ __launch_bounds__(256, 2)
void sdpa_flash_kernel(const float* __restrict__ q,
                       const float* __restrict__ k,
                       const float* __restrict__ v,
                       const float* __restrict__ mask,
                       float* __restrict__ out)
{
    // sK[t]: [krow][d], swizzle key (krow&7)^((krow>>3&1)<<2) on 8-elem
    //        d-blocks (bit3 term keeps 32-row A-frag reads <=2-way).
    // sV[t]: [d][krow] (V^T), key gkey(d) on 8-elem k-blocks.
    __shared__ unsigned short sK[2][64 * 64];
    __shared__ unsigned short sV[2][64 * 64];

    const int tid  = threadIdx.x;
    const int wv   = tid >> 6;                          // 0..3
    const int lane = tid & 63;
    const int l31  = lane & 31;
    const int h    = lane >> 5;                         // 32-lane half
    const int swk  = (lane & 7) ^ (((lane >> 3) & 1) << 2);

    const int fid = blockIdx.x;
    const int bh  = (fid & 7) | ((fid >> 7) << 3);      // XCD-local heads
    const int qb  = ((fid >> 3) & 15) * cQT;
    const int mb  = bh & 1;

    const float L2E = 1.4426950408889634f;

    // ---- Q fragments (B-operand), pre-scaled by 0.125*log2(e) ----
    // lane holds Q[q = wv*32+l31][d = dc*16 + h*8 + 0..7]
    bf16x8 aq[4];
    {
        const float* qp = q + ((size_t)bh * cS + qb + wv * 32 + l31) * cD + h * 8;
#pragma unroll
        for (int dc = 0; dc < 4; ++dc)
            aq[dc] = pack8s(*(const f32x4*)(qp + dc * 16),
                            *(const f32x4*)(qp + dc * 16 + 4), 0.125f * L2E);
    }

    f32x16 acc[2] = {};       // O[q][d]: dg in {0,1} -> d = dg*32 + l31
    float lsum = 0.f;         // row-sum for q = l31 (half-k; merged at end)

    // ---- staging geometry: 256 threads; chunk j = floats j*1024 + tid*4 ----
    const int sr0 = tid >> 4;                 // 0..15
    const int c4  = (tid & 15) << 2;
    const int ka0 = sr0 * 64
        + ((((c4 >> 3) ^ (sr0 & 7) ^ (((sr0 >> 3) & 1) << 2)) << 3))
        + (c4 & 7);
    const float* kg = k + (size_t)bh * cS * cD;
    const float* vg = v + (size_t)bh * cS * cD;
    const float* mq = mask + (size_t)mb * cS * cS
                           + (size_t)(qb + wv * 32 + l31) * cS + h * 4;

    const int g0 = gkey(l31);
    const int g1 = gkey(32 + l31);
    const int vb0 = l31 * 64;
    const int vb1 = (32 + l31) * 64;

    // ---- prologue: stage pair 0 (tiles 0 and 1) directly ----
#pragma unroll
    for (int t = 0; t < 2; ++t)
#pragma unroll
        for (int j = 0; j < 4; ++j) {
            f32x4 kj = *(const f32x4*)(kg + t * 4096 + j * 1024 + tid * 4);
            f32x4 vj = *(const f32x4*)(vg + t * 4096 + j * 1024 + tid * 4);
            *(bf16x4*)&sK[t][ka0 + j * 1024] = pack4(kj);
#pragma unroll
            for (int i = 0; i < 4; ++i) {
                int d = c4 + i;
                sV[t][d * 64 + ((((j * 2) + (sr0 >> 3)) ^ gkey(d)) << 3) + (sr0 & 7)]
                    = bfbits(vj[i]);
            }
        }

    for (int pt = 0; pt < cNP; ++pt) {
        const int base = pt * 2;
        const bool more = (pt + 1 < cNP);
        const int nb = more ? base + 2 : base;      // clamped: uncond. loads

        // ---- prefetch next pair K/V into registers ----
        f32x4 KPe[4], VPe[4], KPo[4], VPo[4];
#pragma unroll
        for (int j = 0; j < 4; ++j) {
            KPe[j] = *(const f32x4*)(kg + (size_t)nb * 4096 + j * 1024 + tid * 4);
            VPe[j] = *(const f32x4*)(vg + (size_t)nb * 4096 + j * 1024 + tid * 4);
            KPo[j] = *(const f32x4*)(kg + (size_t)(nb + 1) * 4096 + j * 1024 + tid * 4);
            VPo[j] = *(const f32x4*)(vg + (size_t)(nb + 1) * 4096 + j * 1024 + tid * 4);
        }

        __syncthreads();                            // pair staged & visible

#pragma unroll
        for (int t = 0; t < 2; ++t) {
            const unsigned short* sKt = sK[t];
            const unsigned short* sVt = sV[t];
#pragma unroll
            for (int gg = 0; gg < 2; ++gg) {
                // ---- mask: lane's q-row, k = (base+t)*64 + gg*32 + klocal ----
                const float* mrow = mq + (size_t)(base + t) * 64 + gg * 32;
                f32x4 mk[4];
#pragma unroll
                for (int j = 0; j < 4; ++j)
                    mk[j] = *(const f32x4*)(mrow + j * 8);

                // ---- QK^T swapped: S^T[k][q], A = K rows gg*32..+31 ----
                const int rb = (gg * 32 + l31) * 64;
                bf16x8 kf[4];
#pragma unroll
                for (int dc = 0; dc < 4; ++dc)
                    kf[dc] = *(const bf16x8*)(&sKt[rb + (((dc * 2 + h) ^ swk) << 3)]);
                f32x16 s = {};
#pragma unroll
                for (int dc = 0; dc < 4; ++dc)
                    s = __builtin_amdgcn_mfma_f32_32x32x16_bf16(kf[dc], aq[dc], s, 0, 0, 0);

                // ---- exp2(S + mask*log2e); k_local(r) = (r&3)+8*(r>>2)+4h ----
                float p[16];
#pragma unroll
                for (int r = 0; r < 16; ++r)
                    p[r] = __builtin_amdgcn_exp2f(fmaf(mk[r >> 2][r & 3], L2E, s[r]));
#pragma unroll
                for (int r = 0; r < 16; ++r)
                    lsum += p[r];

                // ---- pack to bf16 pairs; permlane32_swap builds A-frags ----
                unsigned int pk[8];
#pragma unroll
                for (int i = 0; i < 8; ++i)
                    pk[i] = (unsigned int)bfbits(p[2 * i])
                          | ((unsigned int)bfbits(p[2 * i + 1]) << 16);
                asm("v_permlane32_swap_b32 %0, %1" : "+v"(pk[0]), "+v"(pk[2]));
                asm("v_permlane32_swap_b32 %0, %1" : "+v"(pk[1]), "+v"(pk[3]));
                asm("v_permlane32_swap_b32 %0, %1" : "+v"(pk[4]), "+v"(pk[6]));
                asm("v_permlane32_swap_b32 %0, %1" : "+v"(pk[5]), "+v"(pk[7]));
                u32x4 ua = {pk[0], pk[1], pk[2], pk[3]};
                u32x4 ub = {pk[4], pk[5], pk[6], pk[7]};
                bf16x8 fA0 = __builtin_bit_cast(bf16x8, ua);   // k = gg*32 + 0..15
                bf16x8 fA1 = __builtin_bit_cast(bf16x8, ub);   // k = gg*32 + 16..31

                // ---- PV: O[q][d] += P V, B = V^T reads ----
#pragma unroll
                for (int kc = 0; kc < 2; ++kc) {
                    const int kb = gg * 4 + kc * 2 + h;
                    bf16x8 bv0 = *(const bf16x8*)(&sVt[vb0 + ((kb ^ g0) << 3)]);
                    bf16x8 bv1 = *(const bf16x8*)(&sVt[vb1 + ((kb ^ g1) << 3)]);
                    acc[0] = __builtin_amdgcn_mfma_f32_32x32x16_bf16(
                        kc ? fA1 : fA0, bv0, acc[0], 0, 0, 0);
                    acc[1] = __builtin_amdgcn_mfma_f32_32x32x16_bf16(
                        kc ? fA1 : fA0, bv1, acc[1], 0, 0, 0);
                }
            }
        }

        __syncthreads();                            // pair reads complete

        // ---- stage next pair from registers ----
        if (more) {
#pragma unroll
            for (int j = 0; j < 4; ++j) {
                *(bf16x4*)&sK[0][ka0 + j * 1024] = pack4(KPe[j]);
                *(bf16x4*)&sK[1][ka0 + j * 1024] = pack4(KPo[j]);
#pragma unroll
                for (int i = 0; i < 4; ++i) {
                    int d = c4 + i;
                    int va = d * 64 + ((((j * 2) + (sr0 >> 3)) ^ gkey(d)) << 3) + (sr0 & 7);
                    sV[0][va] = bfbits(VPe[j][i]);
                    sV[1][va] = bfbits(VPo[j][i]);
                }
            }
        }
    }

    // ---- epilogue: merge the two k-halves of lsum, then O = acc / l ----
    lsum += __shfl_xor(lsum, 32, 64);
#pragma unroll
    for (int r = 0; r < 16; ++r) {
        const int qrow = (r & 3) + 8 * (r >> 2) + 4 * h;
        const float rl = 1.0f / __shfl(lsum, qrow, 64);
        float* op = out + ((size_t)bh * cS + qb + wv * 32 + qrow) * cD + l31;
        op[0]  = acc[0][r] * rl;
        op[32] = acc[1][r] * rl;
    }
}

extern "C" void kernel_launch(void* const* d_in, const int* in_sizes, int n_in,
                              void* d_out, int out_size, void* d_ws, size_t ws_size,
                              hipStream_t stream) {
    const float* q = (const float*)d_in[0];
    const float* k = (const float*)d_in[1];
    const float* v = (const float*)d_in[2];
    const float* m = (const float*)d_in[3];
    float* o = (float*)d_out;
    sdpa_flash_kernel<<<dim3(512), 256, 0, stream>>>(q, k, v, m, o);
}